// Round 7
// baseline (216.570 us; speedup 1.0000x reference)
//
#include <hip/hip_runtime.h>
#include <math.h>
#include <stdint.h>

// Problem: B=8, N=1024, ME=1024, D=1024, fp32 in/out.
// a = sigmoid(z @ M @ e^T); A = softmax(a, axis=N); e_out = A @ e.
// Outputs concatenated: e_out [B,N,D] then A [B,N,ME].
//
// Round 14: prefetch pipeline in the (now pure-DMA) GEMMs.
//  - BK=64 double-buffered: issue global_load_lds for tile t+1 BEFORE
//    computing tile t; ONE barrier per K-tile (same barrier rate as R13's
//    BK=128 2-barrier loop). The t+1 loads fly under compute(t); the
//    barrier's vmcnt(0) drain pays only the uncovered remainder.
//    R9/R10's pipeline failures don't apply: no f32 commit, no extra
//    VGPRs, no layout change (proven 0-conflict swz8), no extra barriers.
//  - LDS 64 KB (2 x 16 KB x {A,B}) -> 2 blocks/CU unchanged.
//  - Accumulation order bit-identical -> absmax must stay 0.001464844.
// prep / escale+Ascale / fallback unchanged from R13.

typedef __bf16 bf16_8 __attribute__((ext_vector_type(8)));
typedef __bf16 bf16_4 __attribute__((ext_vector_type(4)));
typedef _Float16 f16_8 __attribute__((ext_vector_type(8)));
typedef _Float16 f16_4 __attribute__((ext_vector_type(4)));
typedef float  f32_4  __attribute__((ext_vector_type(4)));

// ---------------------------------------------------------------------------
__device__ __forceinline__ void gload_lds16(const void* g, void* l) {
    __builtin_amdgcn_global_load_lds(
        (const __attribute__((address_space(1))) void*)g,
        (__attribute__((address_space(3))) void*)l, 16, 0, 0);
}

__device__ __forceinline__ int swz8(int r) { return (r ^ (r >> 2)) & 7; }

// Stage a 128x64 2-byte-elem tile via global_load_lds. Row r, LDS slot s holds
// global 16B-chunk s ^ swz8(r). 1024 chunks = 4 x 256 threads.
template<typename T>
__device__ __forceinline__ void stage_16b(const T* __restrict__ g, int ldK,
                                          int k0, T* lds, int tid) {
#pragma unroll
    for (int t = 0; t < 4; ++t) {
        const int c = t * 256 + tid;
        const int row = c >> 3, slot = c & 7;
        gload_lds16(g + (long long)row * ldK + k0 + (slot ^ swz8(row)) * 8,
                    lds + (t * 256 + (tid >> 6) * 64) * 8);
    }
}

// Fragment LDS offset (2B-elem units): row r, k-chunk cK (0..7).
__device__ __forceinline__ int frag_off(int r, int cK) {
    return r * 64 + ((cK ^ swz8(r)) * 8);
}

// One BK=64 tile: 2 chunks x 16 MFMA (f16).
__device__ __forceinline__ void tile_f16(const _Float16* sA_, const _Float16* sB_,
                                         int wr, int wc, int fr, int q,
                                         f32_4 acc[4][4])
{
#pragma unroll
    for (int ch = 0; ch < 2; ++ch) {
        f16_8 ah[4], bh[4];
#pragma unroll
        for (int i = 0; i < 4; ++i) {
            ah[i] = *(const f16_8*)(sA_ + frag_off(wr + 16 * i + fr, ch * 4 + q));
            bh[i] = *(const f16_8*)(sB_ + frag_off(wc + 16 * i + fr, ch * 4 + q));
        }
#pragma unroll
        for (int i = 0; i < 4; ++i)
#pragma unroll
            for (int j = 0; j < 4; ++j)
                acc[i][j] = __builtin_amdgcn_mfma_f32_16x16x32_f16(ah[i], bh[j], acc[i][j], 0, 0, 0);
    }
}

// One BK=64 tile: 2 chunks x 16 MFMA (bf16).
__device__ __forceinline__ void tile_bf16(const __bf16* sA_, const __bf16* sB_,
                                          int wr, int wc, int fr, int q,
                                          f32_4 acc[4][4])
{
#pragma unroll
    for (int ch = 0; ch < 2; ++ch) {
        bf16_8 ah[4], bh[4];
#pragma unroll
        for (int i = 0; i < 4; ++i) {
            ah[i] = *(const bf16_8*)(sA_ + frag_off(wr + 16 * i + fr, ch * 4 + q));
            bh[i] = *(const bf16_8*)(sB_ + frag_off(wc + 16 * i + fr, ch * 4 + q));
        }
#pragma unroll
        for (int i = 0; i < 4; ++i)
#pragma unroll
            for (int j = 0; j < 4; ++j)
                acc[i][j] = __builtin_amdgcn_mfma_f32_16x16x32_bf16(ah[i], bh[j], acc[i][j], 0, 0, 0);
    }
}

// ---------------------------------------------------------------------------
// GEMM1: zM = z16 @ MT (NT, pure DMA, BK=64 dbuf). Grid (64 rowb, 8 colb):
// XCD = bid%8 -> z16 rows L2-resident per XCD; MT (2 MB) L2-resident.
__global__ __launch_bounds__(256) void gemm1_kernel(
    const _Float16* __restrict__ z16, const _Float16* __restrict__ MT,
    _Float16* __restrict__ zM)
{
    const int D = 1024, NT = 16;
    __shared__ _Float16 sA[2][8192], sB[2][8192];
    const int tid = threadIdx.x, lane = tid & 63, w = tid >> 6;
    const int fr = lane & 15, q = lane >> 4;
    const int wr = (w >> 1) * 64, wc = (w & 1) * 64;
    const int rowb = blockIdx.x, colb = blockIdx.y;

    const _Float16* pA = z16 + (long long)rowb * 128 * D;
    const _Float16* pB = MT  + (long long)colb * 128 * D;

    f32_4 acc[4][4];
#pragma unroll
    for (int i = 0; i < 4; ++i)
#pragma unroll
        for (int j = 0; j < 4; ++j) acc[i][j] = (f32_4){0.f, 0.f, 0.f, 0.f};

    stage_16b(pA, D, 0, sA[0], tid);
    stage_16b(pB, D, 0, sB[0], tid);
    __syncthreads();
    for (int t = 0; t < NT; ++t) {
        const int cur = t & 1;
        if (t + 1 < NT) {
            stage_16b(pA, D, (t + 1) * 64, sA[cur ^ 1], tid);
            stage_16b(pB, D, (t + 1) * 64, sB[cur ^ 1], tid);
        }
        tile_f16(sA[cur], sB[cur], wr, wc, fr, q, acc);
        __syncthreads();
    }

    const int row0 = rowb * 128 + wr;
    const int col0 = colb * 128 + wc;
#pragma unroll
    for (int i = 0; i < 4; ++i)
#pragma unroll
        for (int j = 0; j < 4; ++j) {
            const int col = col0 + 16 * j + fr;
#pragma unroll
            for (int reg = 0; reg < 4; ++reg) {
                const int row = row0 + 16 * i + q * 4 + reg;
                zM[(long long)row * D + col] = (_Float16)acc[i][j][reg];
            }
        }
}

// ---------------------------------------------------------------------------
// GEMM2: P = exp(sigmoid(zM @ e16^T)) per batch (NT, pure DMA, BK=64 dbuf),
// bf16 out + colsum atomics. Grid (8,8,8), batch = blockIdx.x.
__global__ __launch_bounds__(256) void gemm2_kernel(
    const _Float16* __restrict__ zM, const _Float16* __restrict__ e16,
    __bf16* __restrict__ P_bf, float* __restrict__ sums)
{
    const int D = 1024, N = 1024, ME = 1024, NT = 16;
    __shared__ _Float16 sA[2][8192], sB[2][8192];
    const int tid = threadIdx.x, lane = tid & 63, w = tid >> 6;
    const int fr = lane & 15, q = lane >> 4;
    const int wr = (w >> 1) * 64, wc = (w & 1) * 64;
    const int bz = blockIdx.x, rowb = blockIdx.y, colb = blockIdx.z;

    const _Float16* pA = zM  + ((long long)bz * N + rowb * 128) * D;
    const _Float16* pB = e16 + ((long long)bz * ME + colb * 128) * D;

    f32_4 acc[4][4];
#pragma unroll
    for (int i = 0; i < 4; ++i)
#pragma unroll
        for (int j = 0; j < 4; ++j) acc[i][j] = (f32_4){0.f, 0.f, 0.f, 0.f};

    stage_16b(pA, D, 0, sA[0], tid);
    stage_16b(pB, D, 0, sB[0], tid);
    __syncthreads();
    for (int t = 0; t < NT; ++t) {
        const int cur = t & 1;
        if (t + 1 < NT) {
            stage_16b(pA, D, (t + 1) * 64, sA[cur ^ 1], tid);
            stage_16b(pB, D, (t + 1) * 64, sB[cur ^ 1], tid);
        }
        tile_f16(sA[cur], sB[cur], wr, wc, fr, q, acc);
        __syncthreads();
    }

    const int row0 = rowb * 128 + wr;
    const int col0 = colb * 128 + wc;
    float cs[4] = {0.f, 0.f, 0.f, 0.f};
#pragma unroll
    for (int i = 0; i < 4; ++i)
#pragma unroll
        for (int j = 0; j < 4; ++j) {
            const int col = col0 + 16 * j + fr;
#pragma unroll
            for (int reg = 0; reg < 4; ++reg) {
                const int row = row0 + 16 * i + q * 4 + reg;
                float v = acc[i][j][reg];
                const float s = 1.0f / (1.0f + __expf(-v));
                v = __expf(s);
                P_bf[(long long)bz * N * ME + (long long)row * ME + col] = (__bf16)v;
                cs[j] += v;
            }
        }
#pragma unroll
    for (int j = 0; j < 4; ++j) {
        float s = cs[j];
        s += __shfl_xor(s, 16, 64);
        s += __shfl_xor(s, 32, 64);
        if (lane < 16)
            atomicAdd(&sums[bz * ME + col0 + 16 * j + lane], s);
    }
}

// ---------------------------------------------------------------------------
// escale + A-scale. Grid (8, 16, 34):
//   z < 32 : eTs[b][d][m] = (bf16)(e[b][m][d] / colsum[b][m]) (LDS transpose)
//   z >= 32: A = P/s, 64 rows per block (b=x, yb=y<8, half=z-32).
__global__ __launch_bounds__(256) void escale_kernel(
    const float* __restrict__ e, const float* __restrict__ sums,
    __bf16* __restrict__ eTs,
    const __bf16* __restrict__ P_bf, float* __restrict__ Aout)
{
    const int D = 1024, ME = 1024, N = 1024;
    __shared__ float t[64][33];
    const int tid = threadIdx.x;

    if (blockIdx.z >= 32) {   // A = P_bf / s
        if (blockIdx.y >= 8) return;
        const int b = blockIdx.x, yb = blockIdx.y, half = blockIdx.z - 32;
        const long long base = ((long long)b * N + yb * 128 + half * 64) * ME;
        const float4 sv = *(const float4*)(sums + b * ME + tid * 4);
        const float4 rs = make_float4(1.f / sv.x, 1.f / sv.y, 1.f / sv.z, 1.f / sv.w);
        for (int it = 0; it < 64; ++it) {
            const long long o = base + (long long)it * ME + tid * 4;
            bf16_4 p = *(const bf16_4*)(P_bf + o);
            *(float4*)(Aout + o) =
                make_float4((float)p[0] * rs.x, (float)p[1] * rs.y,
                            (float)p[2] * rs.z, (float)p[3] * rs.w);
        }
        return;
    }

    const int b = blockIdx.x, m0 = blockIdx.y * 64, d0 = blockIdx.z * 32;
    const float* eb = e + (long long)b * ME * D;
    const int tx = tid & 31, ty = tid >> 5;   // 8 m-rows per pass
#pragma unroll
    for (int rr = ty; rr < 64; rr += 8)
        t[rr][tx] = eb[(long long)(m0 + rr) * D + d0 + tx];
    const int wx = tid & 63, wy = tid >> 6;   // 4 d-rows per pass
    const float rs = 1.0f / sums[b * ME + m0 + wx];
    __syncthreads();
    __bf16* ob = eTs + (long long)b * D * ME;
#pragma unroll
    for (int dd = wy; dd < 32; dd += 4)
        ob[(long long)(d0 + dd) * ME + m0 + wx] = (__bf16)(t[wx][dd] * rs);
}

// ---------------------------------------------------------------------------
// GEMM3: e_out = P @ eTs (NT bf16 pure-DMA GEMM, BK=64 dbuf). Grid (8,8,8).
__global__ __launch_bounds__(256) void gemm3_kernel(
    const __bf16* __restrict__ P_bf, const __bf16* __restrict__ eTs,
    float* __restrict__ e_out)
{
    const int D = 1024, N = 1024, ME = 1024, NT = 16;
    __shared__ __bf16 sA[2][8192], sB[2][8192];
    const int tid = threadIdx.x, lane = tid & 63, w = tid >> 6;
    const int fr = lane & 15, q = lane >> 4;
    const int wr = (w >> 1) * 64, wc = (w & 1) * 64;
    const int bz = blockIdx.x, rowb = blockIdx.y, colb = blockIdx.z;

    const __bf16* pA = P_bf + ((long long)bz * N + rowb * 128) * ME;
    const __bf16* pB = eTs  + ((long long)bz * D + colb * 128) * ME;

    f32_4 acc[4][4];
#pragma unroll
    for (int i = 0; i < 4; ++i)
#pragma unroll
        for (int j = 0; j < 4; ++j) acc[i][j] = (f32_4){0.f, 0.f, 0.f, 0.f};

    stage_16b(pA, ME, 0, sA[0], tid);
    stage_16b(pB, ME, 0, sB[0], tid);
    __syncthreads();
    for (int t = 0; t < NT; ++t) {
        const int cur = t & 1;
        if (t + 1 < NT) {
            stage_16b(pA, ME, (t + 1) * 64, sA[cur ^ 1], tid);
            stage_16b(pB, ME, (t + 1) * 64, sB[cur ^ 1], tid);
        }
        tile_bf16(sA[cur], sB[cur], wr, wc, fr, q, acc);
        __syncthreads();
    }

    const int row0 = rowb * 128 + wr;
    const int col0 = colb * 128 + wc;
#pragma unroll
    for (int i = 0; i < 4; ++i)
#pragma unroll
        for (int j = 0; j < 4; ++j) {
            const int col = col0 + 16 * j + fr;
#pragma unroll
            for (int reg = 0; reg < 4; ++reg) {
                const int row = row0 + 16 * i + q * 4 + reg;
                e_out[(long long)bz * N * D + (long long)row * D + col] = acc[i][j][reg];
            }
        }
}

// ---------------------------------------------------------------------------
// prep: M^T f16 (1024) + zero sums (8) + e->e16 (2048) + z->z16 (2048).
// Grid 5128.
__global__ __launch_bounds__(256) void prep_kernel(
    const float* __restrict__ M, _Float16* __restrict__ MT,
    const float* __restrict__ e, _Float16* __restrict__ e16,
    const float* __restrict__ z, _Float16* __restrict__ z16,
    float* __restrict__ sums, int D)
{
    __shared__ float t32[32][33];
    const int bid = blockIdx.x, tid = threadIdx.x;
    if (bid < 1024) {
        const int r0 = (bid >> 5) * 32, c0 = (bid & 31) * 32;
        const int tx = tid & 31, ty = tid >> 5;
#pragma unroll
        for (int rr = ty; rr < 32; rr += 8)
            t32[rr][tx] = M[(long long)(r0 + rr) * D + c0 + tx];
        __syncthreads();
#pragma unroll
        for (int cc = ty; cc < 32; cc += 8) {
            const float v = t32[tx][cc];
            MT[(long long)(c0 + cc) * D + r0 + tx] = (_Float16)v;
        }
    } else if (bid < 1032) {
        const int i = ((bid - 1024) * 256 + tid) * 4;
        *(float4*)(sums + i) = make_float4(0.f, 0.f, 0.f, 0.f);
    } else if (bid < 3080) {
        const long long base = (long long)(bid - 1032) * 4096;
#pragma unroll
        for (int p = 0; p < 4; ++p) {
            const long long i = base + (p * 256 + tid) * 4;
            const float4 v = *(const float4*)(e + i);
            f16_4 h;
            h[0] = (_Float16)v.x; h[1] = (_Float16)v.y;
            h[2] = (_Float16)v.z; h[3] = (_Float16)v.w;
            *(f16_4*)(e16 + i) = h;
        }
    } else {
        const long long base = (long long)(bid - 3080) * 4096;
#pragma unroll
        for (int p = 0; p < 4; ++p) {
            const long long i = base + (p * 256 + tid) * 4;
            const float4 v = *(const float4*)(z + i);
            f16_4 h;
            h[0] = (_Float16)v.x; h[1] = (_Float16)v.y;
            h[2] = (_Float16)v.z; h[3] = (_Float16)v.w;
            *(f16_4*)(z16 + i) = h;
        }
    }
}

// ---------------------------------------------------------------------------
// Fallback fp32 path (round-1 kernels).
#define TILE 128
#define KT 8
template<bool BT, int EPI>
__global__ __launch_bounds__(256) void gemm_kernel(
    const float* __restrict__ A, const float* __restrict__ B, float* __restrict__ C,
    long long sA, long long sB, long long sC, int Mrows, int Ncols, int K)
{
    __shared__ float As[KT][TILE + 4];
    __shared__ float Bs[KT][TILE + 4];
    const int bz = blockIdx.z;
    A += (long long)bz * sA; B += (long long)bz * sB; C += (long long)bz * sC;
    const int tid = threadIdx.x;
    const int row0 = blockIdx.y * TILE, col0 = blockIdx.x * TILE;
    const int ld_r = tid >> 1, ld_k4 = (tid & 1) * 4;
    const int bn_k = tid >> 5, bn_c4 = (tid & 31) * 4;
    const int tx = tid & 15, ty = tid >> 4;
    const int c0 = tx * 4, c1 = c0 + 64, r0 = ty * 4, r1 = r0 + 64;
    float acc[8][8];
#pragma unroll
    for (int i = 0; i < 8; i++)
#pragma unroll
        for (int j = 0; j < 8; j++) acc[i][j] = 0.f;
    for (int k0 = 0; k0 < K; k0 += KT) {
        float4 av = *(const float4*)(A + (long long)(row0 + ld_r) * K + k0 + ld_k4);
        float4 bv;
        if (BT) bv = *(const float4*)(B + (long long)(col0 + ld_r) * K + k0 + ld_k4);
        else    bv = *(const float4*)(B + (long long)(k0 + bn_k) * Ncols + col0 + bn_c4);
        __syncthreads();
        As[ld_k4 + 0][ld_r] = av.x; As[ld_k4 + 1][ld_r] = av.y;
        As[ld_k4 + 2][ld_r] = av.z; As[ld_k4 + 3][ld_r] = av.w;
        if (BT) {
            Bs[ld_k4 + 0][ld_r] = bv.x; Bs[ld_k4 + 1][ld_r] = bv.y;
            Bs[ld_k4 + 2][ld_r] = bv.z; Bs[ld_k4 + 3][ld_r] = bv.w;
        } else {
            *(float4*)&Bs[bn_k][bn_c4] = bv;
        }
        __syncthreads();
#pragma unroll
        for (int kk = 0; kk < KT; kk++) {
            float4 a0 = *(const float4*)&As[kk][r0];
            float4 a1 = *(const float4*)&As[kk][r1];
            float4 b0 = *(const float4*)&Bs[kk][c0];
            float4 b1 = *(const float4*)&Bs[kk][c1];
            float ar[8] = {a0.x, a0.y, a0.z, a0.w, a1.x, a1.y, a1.z, a1.w};
            float br[8] = {b0.x, b0.y, b0.z, b0.w, b1.x, b1.y, b1.z, b1.w};
#pragma unroll
            for (int i = 0; i < 8; i++)
#pragma unroll
                for (int j = 0; j < 8; j++) acc[i][j] += ar[i] * br[j];
        }
    }
#pragma unroll
    for (int i = 0; i < 8; i++) {
        const int rr = (i < 4) ? (r0 + i) : (r1 + i - 4);
        float* crow = C + (long long)(row0 + rr) * Ncols + col0;
        float v[8];
#pragma unroll
        for (int j = 0; j < 8; j++) v[j] = acc[i][j];
        if (EPI == 1) {
#pragma unroll
            for (int j = 0; j < 8; j++) {
                float s = 1.0f / (1.0f + __expf(-v[j]));
                v[j] = __expf(s);
            }
        }
        *(float4*)(crow + c0) = make_float4(v[0], v[1], v[2], v[3]);
        *(float4*)(crow + c1) = make_float4(v[4], v[5], v[6], v[7]);
    }
}

__global__ __launch_bounds__(256) void colsum_kernel(
    const float* __restrict__ P, float* __restrict__ sums, int Nn, int Mm, int chunk)
{
    const int g = blockIdx.x * 256 + threadIdx.x;
    const int b = g >> 10;
    const int m = g & 1023;
    const int n0 = blockIdx.y * chunk;
    const float* p = P + (long long)b * Nn * Mm + (long long)n0 * Mm + m;
    float s0 = 0.f, s1 = 0.f, s2 = 0.f, s3 = 0.f;
    for (int n = 0; n < chunk; n += 4) {
        s0 += p[(long long)(n + 0) * Mm];
        s1 += p[(long long)(n + 1) * Mm];
        s2 += p[(long long)(n + 2) * Mm];
        s3 += p[(long long)(n + 3) * Mm];
    }
    atomicAdd(&sums[g], (s0 + s1) + (s2 + s3));
}

__global__ __launch_bounds__(256) void scale_kernel(
    float* __restrict__ P, const float* __restrict__ sums)
{
    const long long base = (blockIdx.x * 256LL + threadIdx.x) * 4;
    const int b = (int)(base >> 20);
    const int col = (int)(base & 1023);
    float4 v = *(float4*)(P + base);
    const float4 s = *(const float4*)(sums + (b << 10) + col);
    v.x /= s.x; v.y /= s.y; v.z /= s.z; v.w /= s.w;
    *(float4*)(P + base) = v;
}

// ---------------------------------------------------------------------------
extern "C" void kernel_launch(void* const* d_in, const int* in_sizes, int n_in,
                              void* d_out, int out_size, void* d_ws, size_t ws_size,
                              hipStream_t stream)
{
    const int B = 8, N = 1024, ME = 1024, D = 1024;
    const float* z = (const float*)d_in[0];   // [B,N,D]
    const float* e = (const float*)d_in[1];   // [B,ME,D]
    const float* M = (const float*)d_in[2];   // [D,D]
    float* out   = (float*)d_out;
    float* e_out = out;                         // [B,N,D]
    float* Aout  = out + (long long)B * N * D;  // [B,N,ME]

    const size_t MB = 1024 * 1024;
    const size_t NEEDED = 52 * MB + (size_t)B * ME * sizeof(float);

    if (ws_size >= NEEDED) {
        char* W = (char*)d_ws;
        _Float16* MT   = (_Float16*)(W);           // 2 MB
        _Float16* zM   = (_Float16*)(W + 4 * MB);  // 16 MB (reused as eTs after gemm2)
        _Float16* e16  = (_Float16*)(W + 20 * MB); // 16 MB
        __bf16*   P_bf = (__bf16*)(W + 36 * MB);   // 16 MB (z16 before gemm2)
        float*    sums = (float*)(W + 52 * MB);    // 32 KB
        _Float16* z16  = (_Float16*)P_bf;          // alias: dead once gemm2 writes P
        __bf16*   eTs  = (__bf16*)zM;              // alias: zM dead after gemm2

        // 1) prep: M^T f16 + zero sums + e16 + z16 casts.
        prep_kernel<<<dim3(5128), 256, 0, stream>>>(M, MT, e, e16, z, z16, sums, D);

        // 2) GEMM1: zM = z16 @ MT (pure DMA, BK=64 dbuf pipeline).
        gemm1_kernel<<<dim3(64, 8, 1), 256, 0, stream>>>(z16, MT, zM);

        // 3) GEMM2: P = exp(sigmoid(zM @ e16^T)) -> bf16 + colsum atomics.
        gemm2_kernel<<<dim3(8, 8, 8), 256, 0, stream>>>(zM, e16, P_bf, sums);

        // 4) escale: eTs = (e/colsum)^T bf16 + A = P/s slices.
        escale_kernel<<<dim3(8, 16, 34), 256, 0, stream>>>(e, sums, eTs, P_bf, Aout);

        // 5) GEMM3: e_out = P @ eTs (pure bf16 DMA, BK=64 dbuf pipeline).
        gemm3_kernel<<<dim3(8, 8, 8), 256, 0, stream>>>(P_bf, eTs, e_out);
    } else {
        // fp32 fallback (round-1 path), needs 32 MB + 32 KB.
        float* zM   = (float*)d_ws;
        float* sums = (float*)((char*)d_ws + (size_t)B * N * D * 4);
        gemm_kernel<false, 0><<<dim3(ME / TILE, (B * N) / TILE, 1), 256, 0, stream>>>(
            z, M, zM, 0, 0, 0, B * N, D, D);
        gemm_kernel<true, 1><<<dim3(ME / TILE, N / TILE, B), 256, 0, stream>>>(
            zM, e, Aout, (long long)N * D, (long long)ME * D, (long long)N * ME, N, ME, D);
        hipMemsetAsync(sums, 0, (size_t)B * ME * sizeof(float), stream);
        colsum_kernel<<<dim3((B * ME) / 256, 8), 256, 0, stream>>>(Aout, sums, N, ME, N / 8);
        scale_kernel<<<dim3((B * N * ME / 4) / 256), 256, 0, stream>>>(Aout, sums);
        gemm_kernel<false, 0><<<dim3(D / TILE, N / TILE, B), 256, 0, stream>>>(
            Aout, e, e_out, (long long)N * ME, (long long)ME * D, (long long)N * D, N, D, ME);
    }
}

// Round 8
// 197.929 us; speedup vs baseline: 1.0942x; 1.0942x over previous
//
#include <hip/hip_runtime.h>
#include <math.h>
#include <stdint.h>

// Problem: B=8, N=1024, ME=1024, D=1024, fp32 in/out.
// a = sigmoid(z @ M @ e^T); A = softmax(a, axis=N); e_out = A @ e.
// Outputs concatenated: e_out [B,N,D] then A [B,N,ME].
//
// Round 15: revert to the R13 skeleton (R14's prefetch pipeline regressed
// 197->217: barrier vmcnt(0) drains the prefetch anyway + halved MLP bursts;
// 3rd failed pipeline attempt -> direction closed at this tile size).
// Deltas on top of R13, scheduling untouched:
//  - P stored f16 (was bf16); eTs f16; gemm3 all-f16 MFMA (same rate).
//    P in [1,e]: f16 gives +3 mantissa bits -> absmax floor should DROP.
//  - escale reads e16 (16 MB) instead of fp32 e (32 MB): -16 MB fetch.
//  - everything else byte-for-byte R13 (BK=128 batch-staged, pure-DMA,
//    swz8 0-conflict layout, XCD-aware gemm1 grid, A-scale in escale).

typedef __bf16 bf16_8 __attribute__((ext_vector_type(8)));
typedef _Float16 f16_8 __attribute__((ext_vector_type(8)));
typedef _Float16 f16_4 __attribute__((ext_vector_type(4)));
typedef float  f32_4  __attribute__((ext_vector_type(4)));

// ---------------------------------------------------------------------------
__device__ __forceinline__ void gload_lds16(const void* g, void* l) {
    __builtin_amdgcn_global_load_lds(
        (const __attribute__((address_space(1))) void*)g,
        (__attribute__((address_space(3))) void*)l, 16, 0, 0);
}

__device__ __forceinline__ int swz8(int r) { return (r ^ (r >> 2)) & 7; }

// Stage a 128x64 2-byte-elem tile via global_load_lds. Row r, LDS slot s holds
// global 16B-chunk s ^ swz8(r). 1024 chunks = 4 x 256 threads.
template<typename T>
__device__ __forceinline__ void stage_16b(const T* __restrict__ g, int ldK,
                                          int k0, T* lds, int tid) {
#pragma unroll
    for (int t = 0; t < 4; ++t) {
        const int c = t * 256 + tid;
        const int row = c >> 3, slot = c & 7;
        gload_lds16(g + (long long)row * ldK + k0 + (slot ^ swz8(row)) * 8,
                    lds + (t * 256 + (tid >> 6) * 64) * 8);
    }
}

// Fragment LDS offset (2B-elem units): row r, k-chunk cK (0..7).
__device__ __forceinline__ int frag_off(int r, int cK) {
    return r * 64 + ((cK ^ swz8(r)) * 8);
}

// One 64-wide K-half: 2 chunks x 16 MFMA (f16).
__device__ __forceinline__ void half_f16(const _Float16* sA_, const _Float16* sB_,
                                         int wr, int wc, int fr, int q,
                                         f32_4 acc[4][4])
{
#pragma unroll
    for (int ch = 0; ch < 2; ++ch) {
        f16_8 ah[4], bh[4];
#pragma unroll
        for (int i = 0; i < 4; ++i) {
            ah[i] = *(const f16_8*)(sA_ + frag_off(wr + 16 * i + fr, ch * 4 + q));
            bh[i] = *(const f16_8*)(sB_ + frag_off(wc + 16 * i + fr, ch * 4 + q));
        }
#pragma unroll
        for (int i = 0; i < 4; ++i)
#pragma unroll
            for (int j = 0; j < 4; ++j)
                acc[i][j] = __builtin_amdgcn_mfma_f32_16x16x32_f16(ah[i], bh[j], acc[i][j], 0, 0, 0);
    }
}

// ---------------------------------------------------------------------------
// GEMM1: zM = z16 @ MT (NT, pure DMA, BK=128). Grid (64 rowb, 8 colb):
// XCD = bid%8 -> z16 rows L2-resident per XCD; MT (2 MB) L2-resident.
__global__ __launch_bounds__(256) void gemm1_kernel(
    const _Float16* __restrict__ z16, const _Float16* __restrict__ MT,
    _Float16* __restrict__ zM)
{
    const int D = 1024;
    __shared__ _Float16 sA0[8192], sA1[8192], sB0[8192], sB1[8192];
    const int tid = threadIdx.x, lane = tid & 63, w = tid >> 6;
    const int fr = lane & 15, q = lane >> 4;
    const int wr = (w >> 1) * 64, wc = (w & 1) * 64;
    const int rowb = blockIdx.x, colb = blockIdx.y;

    const _Float16* pA = z16 + (long long)rowb * 128 * D;
    const _Float16* pB = MT  + (long long)colb * 128 * D;

    f32_4 acc[4][4];
#pragma unroll
    for (int i = 0; i < 4; ++i)
#pragma unroll
        for (int j = 0; j < 4; ++j) acc[i][j] = (f32_4){0.f, 0.f, 0.f, 0.f};

    for (int k0 = 0; k0 < D; k0 += 128) {
        stage_16b(pA, D, k0,      sA0, tid);
        stage_16b(pA, D, k0 + 64, sA1, tid);
        stage_16b(pB, D, k0,      sB0, tid);
        stage_16b(pB, D, k0 + 64, sB1, tid);
        __syncthreads();
        half_f16(sA0, sB0, wr, wc, fr, q, acc);
        half_f16(sA1, sB1, wr, wc, fr, q, acc);
        __syncthreads();
    }

    const int row0 = rowb * 128 + wr;
    const int col0 = colb * 128 + wc;
#pragma unroll
    for (int i = 0; i < 4; ++i)
#pragma unroll
        for (int j = 0; j < 4; ++j) {
            const int col = col0 + 16 * j + fr;
#pragma unroll
            for (int reg = 0; reg < 4; ++reg) {
                const int row = row0 + 16 * i + q * 4 + reg;
                zM[(long long)row * D + col] = (_Float16)acc[i][j][reg];
            }
        }
}

// ---------------------------------------------------------------------------
// GEMM2: P = exp(sigmoid(zM @ e16^T)) per batch (NT, pure DMA, BK=128),
// f16 out + colsum atomics. Grid (8,8,8), batch = blockIdx.x.
__global__ __launch_bounds__(256) void gemm2_kernel(
    const _Float16* __restrict__ zM, const _Float16* __restrict__ e16,
    _Float16* __restrict__ P16, float* __restrict__ sums)
{
    const int D = 1024, N = 1024, ME = 1024;
    __shared__ _Float16 sA0[8192], sA1[8192], sB0[8192], sB1[8192];
    const int tid = threadIdx.x, lane = tid & 63, w = tid >> 6;
    const int fr = lane & 15, q = lane >> 4;
    const int wr = (w >> 1) * 64, wc = (w & 1) * 64;
    const int bz = blockIdx.x, rowb = blockIdx.y, colb = blockIdx.z;

    const _Float16* pA = zM  + ((long long)bz * N + rowb * 128) * D;
    const _Float16* pB = e16 + ((long long)bz * ME + colb * 128) * D;

    f32_4 acc[4][4];
#pragma unroll
    for (int i = 0; i < 4; ++i)
#pragma unroll
        for (int j = 0; j < 4; ++j) acc[i][j] = (f32_4){0.f, 0.f, 0.f, 0.f};

    for (int k0 = 0; k0 < D; k0 += 128) {
        stage_16b(pA, D, k0,      sA0, tid);
        stage_16b(pA, D, k0 + 64, sA1, tid);
        stage_16b(pB, D, k0,      sB0, tid);
        stage_16b(pB, D, k0 + 64, sB1, tid);
        __syncthreads();
        half_f16(sA0, sB0, wr, wc, fr, q, acc);
        half_f16(sA1, sB1, wr, wc, fr, q, acc);
        __syncthreads();
    }

    const int row0 = rowb * 128 + wr;
    const int col0 = colb * 128 + wc;
    float cs[4] = {0.f, 0.f, 0.f, 0.f};
#pragma unroll
    for (int i = 0; i < 4; ++i)
#pragma unroll
        for (int j = 0; j < 4; ++j) {
            const int col = col0 + 16 * j + fr;
#pragma unroll
            for (int reg = 0; reg < 4; ++reg) {
                const int row = row0 + 16 * i + q * 4 + reg;
                float v = acc[i][j][reg];
                const float s = 1.0f / (1.0f + __expf(-v));
                v = __expf(s);
                P16[(long long)bz * N * ME + (long long)row * ME + col] = (_Float16)v;
                cs[j] += v;
            }
        }
#pragma unroll
    for (int j = 0; j < 4; ++j) {
        float s = cs[j];
        s += __shfl_xor(s, 16, 64);
        s += __shfl_xor(s, 32, 64);
        if (lane < 16)
            atomicAdd(&sums[bz * ME + col0 + 16 * j + lane], s);
    }
}

// ---------------------------------------------------------------------------
// escale + A-scale. Grid (8, 16, 34):
//   z < 32 : eTs[b][d][m] = (f16)(e16[b][m][d] / colsum[b][m]) (LDS transpose)
//   z >= 32: A = P/s, 64 rows per block (b=x, yb=y<8, half=z-32).
__global__ __launch_bounds__(256) void escale_kernel(
    const _Float16* __restrict__ e16, const float* __restrict__ sums,
    _Float16* __restrict__ eTs,
    const _Float16* __restrict__ P16, float* __restrict__ Aout)
{
    const int D = 1024, ME = 1024, N = 1024;
    __shared__ float t[64][33];
    const int tid = threadIdx.x;

    if (blockIdx.z >= 32) {   // A = P16 / s
        if (blockIdx.y >= 8) return;
        const int b = blockIdx.x, yb = blockIdx.y, half = blockIdx.z - 32;
        const long long base = ((long long)b * N + yb * 128 + half * 64) * ME;
        const float4 sv = *(const float4*)(sums + b * ME + tid * 4);
        const float4 rs = make_float4(1.f / sv.x, 1.f / sv.y, 1.f / sv.z, 1.f / sv.w);
        for (int it = 0; it < 64; ++it) {
            const long long o = base + (long long)it * ME + tid * 4;
            f16_4 p = *(const f16_4*)(P16 + o);
            *(float4*)(Aout + o) =
                make_float4((float)p[0] * rs.x, (float)p[1] * rs.y,
                            (float)p[2] * rs.z, (float)p[3] * rs.w);
        }
        return;
    }

    const int b = blockIdx.x, m0 = blockIdx.y * 64, d0 = blockIdx.z * 32;
    const _Float16* eb = e16 + (long long)b * ME * D;
    const int tx = tid & 31, ty = tid >> 5;   // 8 m-rows per pass
#pragma unroll
    for (int rr = ty; rr < 64; rr += 8)
        t[rr][tx] = (float)eb[(long long)(m0 + rr) * D + d0 + tx];
    const int wx = tid & 63, wy = tid >> 6;   // 4 d-rows per pass
    const float rs = 1.0f / sums[b * ME + m0 + wx];
    __syncthreads();
    _Float16* ob = eTs + (long long)b * D * ME;
#pragma unroll
    for (int dd = wy; dd < 32; dd += 4)
        ob[(long long)(d0 + dd) * ME + m0 + wx] = (_Float16)(t[wx][dd] * rs);
}

// ---------------------------------------------------------------------------
// GEMM3: e_out = P @ eTs (NT f16 pure-DMA GEMM, BK=128). Grid (8,8,8).
__global__ __launch_bounds__(256) void gemm3_kernel(
    const _Float16* __restrict__ P16, const _Float16* __restrict__ eTs,
    float* __restrict__ e_out)
{
    const int D = 1024, N = 1024, ME = 1024;
    __shared__ _Float16 sA0[8192], sA1[8192], sB0[8192], sB1[8192];
    const int tid = threadIdx.x, lane = tid & 63, w = tid >> 6;
    const int fr = lane & 15, q = lane >> 4;
    const int wr = (w >> 1) * 64, wc = (w & 1) * 64;
    const int bz = blockIdx.x, rowb = blockIdx.y, colb = blockIdx.z;

    const _Float16* pA = P16 + ((long long)bz * N + rowb * 128) * ME;
    const _Float16* pB = eTs + ((long long)bz * D + colb * 128) * ME;

    f32_4 acc[4][4];
#pragma unroll
    for (int i = 0; i < 4; ++i)
#pragma unroll
        for (int j = 0; j < 4; ++j) acc[i][j] = (f32_4){0.f, 0.f, 0.f, 0.f};

    for (int k0 = 0; k0 < ME; k0 += 128) {
        stage_16b(pA, ME, k0,      sA0, tid);
        stage_16b(pA, ME, k0 + 64, sA1, tid);
        stage_16b(pB, ME, k0,      sB0, tid);
        stage_16b(pB, ME, k0 + 64, sB1, tid);
        __syncthreads();
        half_f16(sA0, sB0, wr, wc, fr, q, acc);
        half_f16(sA1, sB1, wr, wc, fr, q, acc);
        __syncthreads();
    }

    const int row0 = rowb * 128 + wr;
    const int col0 = colb * 128 + wc;
#pragma unroll
    for (int i = 0; i < 4; ++i)
#pragma unroll
        for (int j = 0; j < 4; ++j) {
            const int col = col0 + 16 * j + fr;
#pragma unroll
            for (int reg = 0; reg < 4; ++reg) {
                const int row = row0 + 16 * i + q * 4 + reg;
                e_out[(long long)bz * N * D + (long long)row * D + col] = acc[i][j][reg];
            }
        }
}

// ---------------------------------------------------------------------------
// prep: M^T f16 (1024) + zero sums (8) + e->e16 (2048) + z->z16 (2048).
// Grid 5128.
__global__ __launch_bounds__(256) void prep_kernel(
    const float* __restrict__ M, _Float16* __restrict__ MT,
    const float* __restrict__ e, _Float16* __restrict__ e16,
    const float* __restrict__ z, _Float16* __restrict__ z16,
    float* __restrict__ sums, int D)
{
    __shared__ float t32[32][33];
    const int bid = blockIdx.x, tid = threadIdx.x;
    if (bid < 1024) {
        const int r0 = (bid >> 5) * 32, c0 = (bid & 31) * 32;
        const int tx = tid & 31, ty = tid >> 5;
#pragma unroll
        for (int rr = ty; rr < 32; rr += 8)
            t32[rr][tx] = M[(long long)(r0 + rr) * D + c0 + tx];
        __syncthreads();
#pragma unroll
        for (int cc = ty; cc < 32; cc += 8) {
            const float v = t32[tx][cc];
            MT[(long long)(c0 + cc) * D + r0 + tx] = (_Float16)v;
        }
    } else if (bid < 1032) {
        const int i = ((bid - 1024) * 256 + tid) * 4;
        *(float4*)(sums + i) = make_float4(0.f, 0.f, 0.f, 0.f);
    } else if (bid < 3080) {
        const long long base = (long long)(bid - 1032) * 4096;
#pragma unroll
        for (int p = 0; p < 4; ++p) {
            const long long i = base + (p * 256 + tid) * 4;
            const float4 v = *(const float4*)(e + i);
            f16_4 h;
            h[0] = (_Float16)v.x; h[1] = (_Float16)v.y;
            h[2] = (_Float16)v.z; h[3] = (_Float16)v.w;
            *(f16_4*)(e16 + i) = h;
        }
    } else {
        const long long base = (long long)(bid - 3080) * 4096;
#pragma unroll
        for (int p = 0; p < 4; ++p) {
            const long long i = base + (p * 256 + tid) * 4;
            const float4 v = *(const float4*)(z + i);
            f16_4 h;
            h[0] = (_Float16)v.x; h[1] = (_Float16)v.y;
            h[2] = (_Float16)v.z; h[3] = (_Float16)v.w;
            *(f16_4*)(z16 + i) = h;
        }
    }
}

// ---------------------------------------------------------------------------
// Fallback fp32 path (round-1 kernels).
#define TILE 128
#define KT 8
template<bool BT, int EPI>
__global__ __launch_bounds__(256) void gemm_kernel(
    const float* __restrict__ A, const float* __restrict__ B, float* __restrict__ C,
    long long sA, long long sB, long long sC, int Mrows, int Ncols, int K)
{
    __shared__ float As[KT][TILE + 4];
    __shared__ float Bs[KT][TILE + 4];
    const int bz = blockIdx.z;
    A += (long long)bz * sA; B += (long long)bz * sB; C += (long long)bz * sC;
    const int tid = threadIdx.x;
    const int row0 = blockIdx.y * TILE, col0 = blockIdx.x * TILE;
    const int ld_r = tid >> 1, ld_k4 = (tid & 1) * 4;
    const int bn_k = tid >> 5, bn_c4 = (tid & 31) * 4;
    const int tx = tid & 15, ty = tid >> 4;
    const int c0 = tx * 4, c1 = c0 + 64, r0 = ty * 4, r1 = r0 + 64;
    float acc[8][8];
#pragma unroll
    for (int i = 0; i < 8; i++)
#pragma unroll
        for (int j = 0; j < 8; j++) acc[i][j] = 0.f;
    for (int k0 = 0; k0 < K; k0 += KT) {
        float4 av = *(const float4*)(A + (long long)(row0 + ld_r) * K + k0 + ld_k4);
        float4 bv;
        if (BT) bv = *(const float4*)(B + (long long)(col0 + ld_r) * K + k0 + ld_k4);
        else    bv = *(const float4*)(B + (long long)(k0 + bn_k) * Ncols + col0 + bn_c4);
        __syncthreads();
        As[ld_k4 + 0][ld_r] = av.x; As[ld_k4 + 1][ld_r] = av.y;
        As[ld_k4 + 2][ld_r] = av.z; As[ld_k4 + 3][ld_r] = av.w;
        if (BT) {
            Bs[ld_k4 + 0][ld_r] = bv.x; Bs[ld_k4 + 1][ld_r] = bv.y;
            Bs[ld_k4 + 2][ld_r] = bv.z; Bs[ld_k4 + 3][ld_r] = bv.w;
        } else {
            *(float4*)&Bs[bn_k][bn_c4] = bv;
        }
        __syncthreads();
#pragma unroll
        for (int kk = 0; kk < KT; kk++) {
            float4 a0 = *(const float4*)&As[kk][r0];
            float4 a1 = *(const float4*)&As[kk][r1];
            float4 b0 = *(const float4*)&Bs[kk][c0];
            float4 b1 = *(const float4*)&Bs[kk][c1];
            float ar[8] = {a0.x, a0.y, a0.z, a0.w, a1.x, a1.y, a1.z, a1.w};
            float br[8] = {b0.x, b0.y, b0.z, b0.w, b1.x, b1.y, b1.z, b1.w};
#pragma unroll
            for (int i = 0; i < 8; i++)
#pragma unroll
                for (int j = 0; j < 8; j++) acc[i][j] += ar[i] * br[j];
        }
    }
#pragma unroll
    for (int i = 0; i < 8; i++) {
        const int rr = (i < 4) ? (r0 + i) : (r1 + i - 4);
        float* crow = C + (long long)(row0 + rr) * Ncols + col0;
        float v[8];
#pragma unroll
        for (int j = 0; j < 8; j++) v[j] = acc[i][j];
        if (EPI == 1) {
#pragma unroll
            for (int j = 0; j < 8; j++) {
                float s = 1.0f / (1.0f + __expf(-v[j]));
                v[j] = __expf(s);
            }
        }
        *(float4*)(crow + c0) = make_float4(v[0], v[1], v[2], v[3]);
        *(float4*)(crow + c1) = make_float4(v[4], v[5], v[6], v[7]);
    }
}

__global__ __launch_bounds__(256) void colsum_kernel(
    const float* __restrict__ P, float* __restrict__ sums, int Nn, int Mm, int chunk)
{
    const int g = blockIdx.x * 256 + threadIdx.x;
    const int b = g >> 10;
    const int m = g & 1023;
    const int n0 = blockIdx.y * chunk;
    const float* p = P + (long long)b * Nn * Mm + (long long)n0 * Mm + m;
    float s0 = 0.f, s1 = 0.f, s2 = 0.f, s3 = 0.f;
    for (int n = 0; n < chunk; n += 4) {
        s0 += p[(long long)(n + 0) * Mm];
        s1 += p[(long long)(n + 1) * Mm];
        s2 += p[(long long)(n + 2) * Mm];
        s3 += p[(long long)(n + 3) * Mm];
    }
    atomicAdd(&sums[g], (s0 + s1) + (s2 + s3));
}

__global__ __launch_bounds__(256) void scale_kernel(
    float* __restrict__ P, const float* __restrict__ sums)
{
    const long long base = (blockIdx.x * 256LL + threadIdx.x) * 4;
    const int b = (int)(base >> 20);
    const int col = (int)(base & 1023);
    float4 v = *(float4*)(P + base);
    const float4 s = *(const float4*)(sums + (b << 10) + col);
    v.x /= s.x; v.y /= s.y; v.z /= s.z; v.w /= s.w;
    *(float4*)(P + base) = v;
}

// ---------------------------------------------------------------------------
extern "C" void kernel_launch(void* const* d_in, const int* in_sizes, int n_in,
                              void* d_out, int out_size, void* d_ws, size_t ws_size,
                              hipStream_t stream)
{
    const int B = 8, N = 1024, ME = 1024, D = 1024;
    const float* z = (const float*)d_in[0];   // [B,N,D]
    const float* e = (const float*)d_in[1];   // [B,ME,D]
    const float* M = (const float*)d_in[2];   // [D,D]
    float* out   = (float*)d_out;
    float* e_out = out;                         // [B,N,D]
    float* Aout  = out + (long long)B * N * D;  // [B,N,ME]

    const size_t MB = 1024 * 1024;
    const size_t NEEDED = 52 * MB + (size_t)B * ME * sizeof(float);

    if (ws_size >= NEEDED) {
        char* W = (char*)d_ws;
        _Float16* MT   = (_Float16*)(W);           // 2 MB
        _Float16* zM   = (_Float16*)(W + 4 * MB);  // 16 MB (reused as eTs after gemm2)
        _Float16* e16  = (_Float16*)(W + 20 * MB); // 16 MB
        _Float16* P16  = (_Float16*)(W + 36 * MB); // 16 MB (z16 before gemm2)
        float*    sums = (float*)(W + 52 * MB);    // 32 KB
        _Float16* z16  = P16;                      // alias: dead once gemm2 writes P
        _Float16* eTs  = zM;                       // alias: zM dead after gemm2

        // 1) prep: M^T f16 + zero sums + e16 + z16 casts.
        prep_kernel<<<dim3(5128), 256, 0, stream>>>(M, MT, e, e16, z, z16, sums, D);

        // 2) GEMM1: zM = z16 @ MT (pure DMA, BK=128).
        gemm1_kernel<<<dim3(64, 8, 1), 256, 0, stream>>>(z16, MT, zM);

        // 3) GEMM2: P = exp(sigmoid(zM @ e16^T)) -> f16 + colsum atomics.
        gemm2_kernel<<<dim3(8, 8, 8), 256, 0, stream>>>(zM, e16, P16, sums);

        // 4) escale: eTs = (e16/colsum)^T f16 + A = P/s slices.
        escale_kernel<<<dim3(8, 16, 34), 256, 0, stream>>>(e16, sums, eTs, P16, Aout);

        // 5) GEMM3: e_out = P @ eTs (pure f16 DMA, BK=128).
        gemm3_kernel<<<dim3(8, 8, 8), 256, 0, stream>>>(P16, eTs, e_out);
    } else {
        // fp32 fallback (round-1 path), needs 32 MB + 32 KB.
        float* zM   = (float*)d_ws;
        float* sums = (float*)((char*)d_ws + (size_t)B * N * D * 4);
        gemm_kernel<false, 0><<<dim3(ME / TILE, (B * N) / TILE, 1), 256, 0, stream>>>(
            z, M, zM, 0, 0, 0, B * N, D, D);
        gemm_kernel<true, 1><<<dim3(ME / TILE, N / TILE, B), 256, 0, stream>>>(
            zM, e, Aout, (long long)N * D, (long long)ME * D, (long long)N * ME, N, ME, D);
        hipMemsetAsync(sums, 0, (size_t)B * ME * sizeof(float), stream);
        colsum_kernel<<<dim3((B * ME) / 256, 8), 256, 0, stream>>>(Aout, sums, N, ME, N / 8);
        scale_kernel<<<dim3((B * N * ME / 4) / 256), 256, 0, stream>>>(Aout, sums);
        gemm_kernel<false, 0><<<dim3(D / TILE, N / TILE, B), 256, 0, stream>>>(
            Aout, e, e_out, (long long)N * ME, (long long)ME * D, (long long)N * D, N, D, ME);
    }
}

// Round 9
// 196.169 us; speedup vs baseline: 1.1040x; 1.0090x over previous
//
#include <hip/hip_runtime.h>
#include <math.h>
#include <stdint.h>

// Problem: B=8, N=1024, ME=1024, D=1024, fp32 in/out.
// a = sigmoid(z @ M @ e^T); A = softmax(a, axis=N); e_out = A @ e.
// Outputs concatenated: e_out [B,N,D] then A [B,N,ME].
//
// Round 16: wave re-partition for occupancy. R15 confirmed GEMMs are
// latency-bound at 8 waves/CU (2 blocks x 4 waves, MfmaUtil ~20%).
//  - Same 128x128 tile, BK=128, same grid, same swz8 layout, same staged
//    bytes, same per-output MFMA chain (absmax must stay bit-identical
//    0.001464844) — but 512 threads/block: 8 waves of 64x32 each.
//    => 16 waves/CU = 4 waves/SIMD (2x latency hiding), acc 32 VGPR,
//    __launch_bounds__(512,4) caps VGPR at 128 for 4 waves/EU.
//  - stage_16b_512: 2 passes x 512 threads (same chunk->LDS mapping).
//  - per-CU in-flight DMA unchanged (2 blk x 512 thr x 8 x 16B = 128 KB).
// prep / escale+Ascale / fallback byte-for-byte R15.

typedef __bf16 bf16_8 __attribute__((ext_vector_type(8)));
typedef _Float16 f16_8 __attribute__((ext_vector_type(8)));
typedef _Float16 f16_4 __attribute__((ext_vector_type(4)));
typedef float  f32_4  __attribute__((ext_vector_type(4)));

// ---------------------------------------------------------------------------
__device__ __forceinline__ void gload_lds16(const void* g, void* l) {
    __builtin_amdgcn_global_load_lds(
        (const __attribute__((address_space(1))) void*)g,
        (__attribute__((address_space(3))) void*)l, 16, 0, 0);
}

__device__ __forceinline__ int swz8(int r) { return (r ^ (r >> 2)) & 7; }

// Stage a 128x64 f16 tile via global_load_lds with 512 threads (2 passes).
// Chunk c -> LDS element offset c*8; source chunk (c&7)^swz8(c>>3) of row c>>3.
__device__ __forceinline__ void stage_16b_512(const _Float16* __restrict__ g,
                                              int ldK, int k0, _Float16* lds,
                                              int tid) {
#pragma unroll
    for (int t = 0; t < 2; ++t) {
        const int c = t * 512 + tid;
        const int row = c >> 3, slot = c & 7;
        gload_lds16(g + (long long)row * ldK + k0 + (slot ^ swz8(row)) * 8,
                    lds + (t * 512 + (tid & ~63)) * 8);
    }
}

// Fragment LDS offset (2B-elem units): row r, k-chunk cK (0..7).
__device__ __forceinline__ int frag_off(int r, int cK) {
    return r * 64 + ((cK ^ swz8(r)) * 8);
}

// One 64-wide K-half for a 64x32 wave subtile: 2 chunks x 8 MFMA (f16).
__device__ __forceinline__ void half_f16_w(const _Float16* sA_, const _Float16* sB_,
                                           int wr, int wc, int fr, int q,
                                           f32_4 acc[4][2])
{
#pragma unroll
    for (int ch = 0; ch < 2; ++ch) {
        f16_8 ah[4], bh[2];
#pragma unroll
        for (int i = 0; i < 4; ++i)
            ah[i] = *(const f16_8*)(sA_ + frag_off(wr + 16 * i + fr, ch * 4 + q));
#pragma unroll
        for (int j = 0; j < 2; ++j)
            bh[j] = *(const f16_8*)(sB_ + frag_off(wc + 16 * j + fr, ch * 4 + q));
#pragma unroll
        for (int i = 0; i < 4; ++i)
#pragma unroll
            for (int j = 0; j < 2; ++j)
                acc[i][j] = __builtin_amdgcn_mfma_f32_16x16x32_f16(ah[i], bh[j], acc[i][j], 0, 0, 0);
    }
}

// ---------------------------------------------------------------------------
// GEMM1: zM = z16 @ MT (NT, pure DMA, BK=128, 512 thr / 8 waves).
// Grid (64 rowb, 8 colb): XCD = bid%8 -> z16 rows L2-resident per XCD.
__global__ __launch_bounds__(512, 4) void gemm1_kernel(
    const _Float16* __restrict__ z16, const _Float16* __restrict__ MT,
    _Float16* __restrict__ zM)
{
    const int D = 1024;
    __shared__ _Float16 sA0[8192], sA1[8192], sB0[8192], sB1[8192];
    const int tid = threadIdx.x, lane = tid & 63, w = tid >> 6;
    const int fr = lane & 15, q = lane >> 4;
    const int wr = (w >> 2) * 64, wc = (w & 3) * 32;
    const int rowb = blockIdx.x, colb = blockIdx.y;

    const _Float16* pA = z16 + (long long)rowb * 128 * D;
    const _Float16* pB = MT  + (long long)colb * 128 * D;

    f32_4 acc[4][2];
#pragma unroll
    for (int i = 0; i < 4; ++i)
#pragma unroll
        for (int j = 0; j < 2; ++j) acc[i][j] = (f32_4){0.f, 0.f, 0.f, 0.f};

    for (int k0 = 0; k0 < D; k0 += 128) {
        stage_16b_512(pA, D, k0,      sA0, tid);
        stage_16b_512(pA, D, k0 + 64, sA1, tid);
        stage_16b_512(pB, D, k0,      sB0, tid);
        stage_16b_512(pB, D, k0 + 64, sB1, tid);
        __syncthreads();
        half_f16_w(sA0, sB0, wr, wc, fr, q, acc);
        half_f16_w(sA1, sB1, wr, wc, fr, q, acc);
        __syncthreads();
    }

    const int row0 = rowb * 128 + wr;
    const int col0 = colb * 128 + wc;
#pragma unroll
    for (int i = 0; i < 4; ++i)
#pragma unroll
        for (int j = 0; j < 2; ++j) {
            const int col = col0 + 16 * j + fr;
#pragma unroll
            for (int reg = 0; reg < 4; ++reg) {
                const int row = row0 + 16 * i + q * 4 + reg;
                zM[(long long)row * D + col] = (_Float16)acc[i][j][reg];
            }
        }
}

// ---------------------------------------------------------------------------
// GEMM2: P = exp(sigmoid(zM @ e16^T)) per batch (NT, pure DMA, BK=128,
// 512 thr / 8 waves), f16 out + colsum atomics. Grid (8,8,8), batch = x.
__global__ __launch_bounds__(512, 4) void gemm2_kernel(
    const _Float16* __restrict__ zM, const _Float16* __restrict__ e16,
    _Float16* __restrict__ P16, float* __restrict__ sums)
{
    const int D = 1024, N = 1024, ME = 1024;
    __shared__ _Float16 sA0[8192], sA1[8192], sB0[8192], sB1[8192];
    const int tid = threadIdx.x, lane = tid & 63, w = tid >> 6;
    const int fr = lane & 15, q = lane >> 4;
    const int wr = (w >> 2) * 64, wc = (w & 3) * 32;
    const int bz = blockIdx.x, rowb = blockIdx.y, colb = blockIdx.z;

    const _Float16* pA = zM  + ((long long)bz * N + rowb * 128) * D;
    const _Float16* pB = e16 + ((long long)bz * ME + colb * 128) * D;

    f32_4 acc[4][2];
#pragma unroll
    for (int i = 0; i < 4; ++i)
#pragma unroll
        for (int j = 0; j < 2; ++j) acc[i][j] = (f32_4){0.f, 0.f, 0.f, 0.f};

    for (int k0 = 0; k0 < D; k0 += 128) {
        stage_16b_512(pA, D, k0,      sA0, tid);
        stage_16b_512(pA, D, k0 + 64, sA1, tid);
        stage_16b_512(pB, D, k0,      sB0, tid);
        stage_16b_512(pB, D, k0 + 64, sB1, tid);
        __syncthreads();
        half_f16_w(sA0, sB0, wr, wc, fr, q, acc);
        half_f16_w(sA1, sB1, wr, wc, fr, q, acc);
        __syncthreads();
    }

    const int row0 = rowb * 128 + wr;
    const int col0 = colb * 128 + wc;
    float cs[2] = {0.f, 0.f};
#pragma unroll
    for (int i = 0; i < 4; ++i)
#pragma unroll
        for (int j = 0; j < 2; ++j) {
            const int col = col0 + 16 * j + fr;
#pragma unroll
            for (int reg = 0; reg < 4; ++reg) {
                const int row = row0 + 16 * i + q * 4 + reg;
                float v = acc[i][j][reg];
                const float s = 1.0f / (1.0f + __expf(-v));
                v = __expf(s);
                P16[(long long)bz * N * ME + (long long)row * ME + col] = (_Float16)v;
                cs[j] += v;
            }
        }
#pragma unroll
    for (int j = 0; j < 2; ++j) {
        float s = cs[j];
        s += __shfl_xor(s, 16, 64);
        s += __shfl_xor(s, 32, 64);
        if (lane < 16)
            atomicAdd(&sums[bz * ME + col0 + 16 * j + lane], s);
    }
}

// ---------------------------------------------------------------------------
// escale + A-scale. Grid (8, 16, 34):
//   z < 32 : eTs[b][d][m] = (f16)(e16[b][m][d] / colsum[b][m]) (LDS transpose)
//   z >= 32: A = P/s, 64 rows per block (b=x, yb=y<8, half=z-32).
__global__ __launch_bounds__(256) void escale_kernel(
    const _Float16* __restrict__ e16, const float* __restrict__ sums,
    _Float16* __restrict__ eTs,
    const _Float16* __restrict__ P16, float* __restrict__ Aout)
{
    const int D = 1024, ME = 1024, N = 1024;
    __shared__ float t[64][33];
    const int tid = threadIdx.x;

    if (blockIdx.z >= 32) {   // A = P16 / s
        if (blockIdx.y >= 8) return;
        const int b = blockIdx.x, yb = blockIdx.y, half = blockIdx.z - 32;
        const long long base = ((long long)b * N + yb * 128 + half * 64) * ME;
        const float4 sv = *(const float4*)(sums + b * ME + tid * 4);
        const float4 rs = make_float4(1.f / sv.x, 1.f / sv.y, 1.f / sv.z, 1.f / sv.w);
        for (int it = 0; it < 64; ++it) {
            const long long o = base + (long long)it * ME + tid * 4;
            f16_4 p = *(const f16_4*)(P16 + o);
            *(float4*)(Aout + o) =
                make_float4((float)p[0] * rs.x, (float)p[1] * rs.y,
                            (float)p[2] * rs.z, (float)p[3] * rs.w);
        }
        return;
    }

    const int b = blockIdx.x, m0 = blockIdx.y * 64, d0 = blockIdx.z * 32;
    const _Float16* eb = e16 + (long long)b * ME * D;
    const int tx = tid & 31, ty = tid >> 5;   // 8 m-rows per pass
#pragma unroll
    for (int rr = ty; rr < 64; rr += 8)
        t[rr][tx] = (float)eb[(long long)(m0 + rr) * D + d0 + tx];
    const int wx = tid & 63, wy = tid >> 6;   // 4 d-rows per pass
    const float rs = 1.0f / sums[b * ME + m0 + wx];
    __syncthreads();
    _Float16* ob = eTs + (long long)b * D * ME;
#pragma unroll
    for (int dd = wy; dd < 32; dd += 4)
        ob[(long long)(d0 + dd) * ME + m0 + wx] = (_Float16)(t[wx][dd] * rs);
}

// ---------------------------------------------------------------------------
// GEMM3: e_out = P @ eTs (NT f16 pure-DMA GEMM, BK=128, 512 thr / 8 waves).
// Grid (8,8,8).
__global__ __launch_bounds__(512, 4) void gemm3_kernel(
    const _Float16* __restrict__ P16, const _Float16* __restrict__ eTs,
    float* __restrict__ e_out)
{
    const int D = 1024, N = 1024, ME = 1024;
    __shared__ _Float16 sA0[8192], sA1[8192], sB0[8192], sB1[8192];
    const int tid = threadIdx.x, lane = tid & 63, w = tid >> 6;
    const int fr = lane & 15, q = lane >> 4;
    const int wr = (w >> 2) * 64, wc = (w & 3) * 32;
    const int bz = blockIdx.x, rowb = blockIdx.y, colb = blockIdx.z;

    const _Float16* pA = P16 + ((long long)bz * N + rowb * 128) * ME;
    const _Float16* pB = eTs + ((long long)bz * D + colb * 128) * ME;

    f32_4 acc[4][2];
#pragma unroll
    for (int i = 0; i < 4; ++i)
#pragma unroll
        for (int j = 0; j < 2; ++j) acc[i][j] = (f32_4){0.f, 0.f, 0.f, 0.f};

    for (int k0 = 0; k0 < ME; k0 += 128) {
        stage_16b_512(pA, ME, k0,      sA0, tid);
        stage_16b_512(pA, ME, k0 + 64, sA1, tid);
        stage_16b_512(pB, ME, k0,      sB0, tid);
        stage_16b_512(pB, ME, k0 + 64, sB1, tid);
        __syncthreads();
        half_f16_w(sA0, sB0, wr, wc, fr, q, acc);
        half_f16_w(sA1, sB1, wr, wc, fr, q, acc);
        __syncthreads();
    }

    const int row0 = rowb * 128 + wr;
    const int col0 = colb * 128 + wc;
#pragma unroll
    for (int i = 0; i < 4; ++i)
#pragma unroll
        for (int j = 0; j < 2; ++j) {
            const int col = col0 + 16 * j + fr;
#pragma unroll
            for (int reg = 0; reg < 4; ++reg) {
                const int row = row0 + 16 * i + q * 4 + reg;
                e_out[(long long)bz * N * D + (long long)row * D + col] = acc[i][j][reg];
            }
        }
}

// ---------------------------------------------------------------------------
// prep: M^T f16 (1024) + zero sums (8) + e->e16 (2048) + z->z16 (2048).
// Grid 5128.
__global__ __launch_bounds__(256) void prep_kernel(
    const float* __restrict__ M, _Float16* __restrict__ MT,
    const float* __restrict__ e, _Float16* __restrict__ e16,
    const float* __restrict__ z, _Float16* __restrict__ z16,
    float* __restrict__ sums, int D)
{
    __shared__ float t32[32][33];
    const int bid = blockIdx.x, tid = threadIdx.x;
    if (bid < 1024) {
        const int r0 = (bid >> 5) * 32, c0 = (bid & 31) * 32;
        const int tx = tid & 31, ty = tid >> 5;
#pragma unroll
        for (int rr = ty; rr < 32; rr += 8)
            t32[rr][tx] = M[(long long)(r0 + rr) * D + c0 + tx];
        __syncthreads();
#pragma unroll
        for (int cc = ty; cc < 32; cc += 8) {
            const float v = t32[tx][cc];
            MT[(long long)(c0 + cc) * D + r0 + tx] = (_Float16)v;
        }
    } else if (bid < 1032) {
        const int i = ((bid - 1024) * 256 + tid) * 4;
        *(float4*)(sums + i) = make_float4(0.f, 0.f, 0.f, 0.f);
    } else if (bid < 3080) {
        const long long base = (long long)(bid - 1032) * 4096;
#pragma unroll
        for (int p = 0; p < 4; ++p) {
            const long long i = base + (p * 256 + tid) * 4;
            const float4 v = *(const float4*)(e + i);
            f16_4 h;
            h[0] = (_Float16)v.x; h[1] = (_Float16)v.y;
            h[2] = (_Float16)v.z; h[3] = (_Float16)v.w;
            *(f16_4*)(e16 + i) = h;
        }
    } else {
        const long long base = (long long)(bid - 3080) * 4096;
#pragma unroll
        for (int p = 0; p < 4; ++p) {
            const long long i = base + (p * 256 + tid) * 4;
            const float4 v = *(const float4*)(z + i);
            f16_4 h;
            h[0] = (_Float16)v.x; h[1] = (_Float16)v.y;
            h[2] = (_Float16)v.z; h[3] = (_Float16)v.w;
            *(f16_4*)(z16 + i) = h;
        }
    }
}

// ---------------------------------------------------------------------------
// Fallback fp32 path (round-1 kernels).
#define TILE 128
#define KT 8
template<bool BT, int EPI>
__global__ __launch_bounds__(256) void gemm_kernel(
    const float* __restrict__ A, const float* __restrict__ B, float* __restrict__ C,
    long long sA, long long sB, long long sC, int Mrows, int Ncols, int K)
{
    __shared__ float As[KT][TILE + 4];
    __shared__ float Bs[KT][TILE + 4];
    const int bz = blockIdx.z;
    A += (long long)bz * sA; B += (long long)bz * sB; C += (long long)bz * sC;
    const int tid = threadIdx.x;
    const int row0 = blockIdx.y * TILE, col0 = blockIdx.x * TILE;
    const int ld_r = tid >> 1, ld_k4 = (tid & 1) * 4;
    const int bn_k = tid >> 5, bn_c4 = (tid & 31) * 4;
    const int tx = tid & 15, ty = tid >> 4;
    const int c0 = tx * 4, c1 = c0 + 64, r0 = ty * 4, r1 = r0 + 64;
    float acc[8][8];
#pragma unroll
    for (int i = 0; i < 8; i++)
#pragma unroll
        for (int j = 0; j < 8; j++) acc[i][j] = 0.f;
    for (int k0 = 0; k0 < K; k0 += KT) {
        float4 av = *(const float4*)(A + (long long)(row0 + ld_r) * K + k0 + ld_k4);
        float4 bv;
        if (BT) bv = *(const float4*)(B + (long long)(col0 + ld_r) * K + k0 + ld_k4);
        else    bv = *(const float4*)(B + (long long)(k0 + bn_k) * Ncols + col0 + bn_c4);
        __syncthreads();
        As[ld_k4 + 0][ld_r] = av.x; As[ld_k4 + 1][ld_r] = av.y;
        As[ld_k4 + 2][ld_r] = av.z; As[ld_k4 + 3][ld_r] = av.w;
        if (BT) {
            Bs[ld_k4 + 0][ld_r] = bv.x; Bs[ld_k4 + 1][ld_r] = bv.y;
            Bs[ld_k4 + 2][ld_r] = bv.z; Bs[ld_k4 + 3][ld_r] = bv.w;
        } else {
            *(float4*)&Bs[bn_k][bn_c4] = bv;
        }
        __syncthreads();
#pragma unroll
        for (int kk = 0; kk < KT; kk++) {
            float4 a0 = *(const float4*)&As[kk][r0];
            float4 a1 = *(const float4*)&As[kk][r1];
            float4 b0 = *(const float4*)&Bs[kk][c0];
            float4 b1 = *(const float4*)&Bs[kk][c1];
            float ar[8] = {a0.x, a0.y, a0.z, a0.w, a1.x, a1.y, a1.z, a1.w};
            float br[8] = {b0.x, b0.y, b0.z, b0.w, b1.x, b1.y, b1.z, b1.w};
#pragma unroll
            for (int i = 0; i < 8; i++)
#pragma unroll
                for (int j = 0; j < 8; j++) acc[i][j] += ar[i] * br[j];
        }
    }
#pragma unroll
    for (int i = 0; i < 8; i++) {
        const int rr = (i < 4) ? (r0 + i) : (r1 + i - 4);
        float* crow = C + (long long)(row0 + rr) * Ncols + col0;
        float v[8];
#pragma unroll
        for (int j = 0; j < 8; j++) v[j] = acc[i][j];
        if (EPI == 1) {
#pragma unroll
            for (int j = 0; j < 8; j++) {
                float s = 1.0f / (1.0f + __expf(-v[j]));
                v[j] = __expf(s);
            }
        }
        *(float4*)(crow + c0) = make_float4(v[0], v[1], v[2], v[3]);
        *(float4*)(crow + c1) = make_float4(v[4], v[5], v[6], v[7]);
    }
}

__global__ __launch_bounds__(256) void colsum_kernel(
    const float* __restrict__ P, float* __restrict__ sums, int Nn, int Mm, int chunk)
{
    const int g = blockIdx.x * 256 + threadIdx.x;
    const int b = g >> 10;
    const int m = g & 1023;
    const int n0 = blockIdx.y * chunk;
    const float* p = P + (long long)b * Nn * Mm + (long long)n0 * Mm + m;
    float s0 = 0.f, s1 = 0.f, s2 = 0.f, s3 = 0.f;
    for (int n = 0; n < chunk; n += 4) {
        s0 += p[(long long)(n + 0) * Mm];
        s1 += p[(long long)(n + 1) * Mm];
        s2 += p[(long long)(n + 2) * Mm];
        s3 += p[(long long)(n + 3) * Mm];
    }
    atomicAdd(&sums[g], (s0 + s1) + (s2 + s3));
}

__global__ __launch_bounds__(256) void scale_kernel(
    float* __restrict__ P, const float* __restrict__ sums)
{
    const long long base = (blockIdx.x * 256LL + threadIdx.x) * 4;
    const int b = (int)(base >> 20);
    const int col = (int)(base & 1023);
    float4 v = *(float4*)(P + base);
    const float4 s = *(const float4*)(sums + (b << 10) + col);
    v.x /= s.x; v.y /= s.y; v.z /= s.z; v.w /= s.w;
    *(float4*)(P + base) = v;
}

// ---------------------------------------------------------------------------
extern "C" void kernel_launch(void* const* d_in, const int* in_sizes, int n_in,
                              void* d_out, int out_size, void* d_ws, size_t ws_size,
                              hipStream_t stream)
{
    const int B = 8, N = 1024, ME = 1024, D = 1024;
    const float* z = (const float*)d_in[0];   // [B,N,D]
    const float* e = (const float*)d_in[1];   // [B,ME,D]
    const float* M = (const float*)d_in[2];   // [D,D]
    float* out   = (float*)d_out;
    float* e_out = out;                         // [B,N,D]
    float* Aout  = out + (long long)B * N * D;  // [B,N,ME]

    const size_t MB = 1024 * 1024;
    const size_t NEEDED = 52 * MB + (size_t)B * ME * sizeof(float);

    if (ws_size >= NEEDED) {
        char* W = (char*)d_ws;
        _Float16* MT   = (_Float16*)(W);           // 2 MB
        _Float16* zM   = (_Float16*)(W + 4 * MB);  // 16 MB (reused as eTs after gemm2)
        _Float16* e16  = (_Float16*)(W + 20 * MB); // 16 MB
        _Float16* P16  = (_Float16*)(W + 36 * MB); // 16 MB (z16 before gemm2)
        float*    sums = (float*)(W + 52 * MB);    // 32 KB
        _Float16* z16  = P16;                      // alias: dead once gemm2 writes P
        _Float16* eTs  = zM;                       // alias: zM dead after gemm2

        // 1) prep: M^T f16 + zero sums + e16 + z16 casts.
        prep_kernel<<<dim3(5128), 256, 0, stream>>>(M, MT, e, e16, z, z16, sums, D);

        // 2) GEMM1: zM = z16 @ MT (pure DMA, BK=128, 8 waves).
        gemm1_kernel<<<dim3(64, 8, 1), 512, 0, stream>>>(z16, MT, zM);

        // 3) GEMM2: P = exp(sigmoid(zM @ e16^T)) -> f16 + colsum atomics.
        gemm2_kernel<<<dim3(8, 8, 8), 512, 0, stream>>>(zM, e16, P16, sums);

        // 4) escale: eTs = (e16/colsum)^T f16 + A = P/s slices.
        escale_kernel<<<dim3(8, 16, 34), 256, 0, stream>>>(e16, sums, eTs, P16, Aout);

        // 5) GEMM3: e_out = P @ eTs (pure f16 DMA, BK=128, 8 waves).
        gemm3_kernel<<<dim3(8, 8, 8), 512, 0, stream>>>(P16, eTs, e_out);
    } else {
        // fp32 fallback (round-1 path), needs 32 MB + 32 KB.
        float* zM   = (float*)d_ws;
        float* sums = (float*)((char*)d_ws + (size_t)B * N * D * 4);
        gemm_kernel<false, 0><<<dim3(ME / TILE, (B * N) / TILE, 1), 256, 0, stream>>>(
            z, M, zM, 0, 0, 0, B * N, D, D);
        gemm_kernel<true, 1><<<dim3(ME / TILE, N / TILE, B), 256, 0, stream>>>(
            zM, e, Aout, (long long)N * D, (long long)ME * D, (long long)N * ME, N, ME, D);
        hipMemsetAsync(sums, 0, (size_t)B * ME * sizeof(float), stream);
        colsum_kernel<<<dim3((B * ME) / 256, 8), 256, 0, stream>>>(Aout, sums, N, ME, N / 8);
        scale_kernel<<<dim3((B * N * ME / 4) / 256), 256, 0, stream>>>(Aout, sums);
        gemm_kernel<false, 0><<<dim3(D / TILE, N / TILE, B), 256, 0, stream>>>(
            Aout, e, e_out, (long long)N * ME, (long long)ME * D, (long long)N * D, N, D, ME);
    }
}